// Round 1
// 807.770 us; speedup vs baseline: 1.1914x; 1.1914x over previous
//
#include <hip/hip_runtime.h>
#include <cstdint>
#include <cstddef>

// SAGE 3-layer GNN, MI355X gfx950 — round 4:
//  * GEMM rewritten: W-resident-in-LDS (64KB/phase), A-frags loaded straight
//    global->VGPR (coalesced 16rows x 64B per wave), ZERO barriers in K-loop.
//    Old version drained vmcnt(0) at every BK=32 step re-staging W (MfmaUtil 8%).
//  * fill_csr: 4 dst-range passes so scattered col_idx writes stay L2-resident
//    (was 105MB HBM writeback for a 6.4MB array).

#define N_NODES 100000
#define N_EDGES 1600000

#define SCAN_BLOCKS 256
#define SCAN_T 256
#define FILL_PASSES 4

typedef unsigned short ushort;
typedef unsigned int uint;
typedef __attribute__((ext_vector_type(8))) short short8;
typedef __attribute__((ext_vector_type(4))) float floatx4;

#define AS1 __attribute__((address_space(1)))
#define AS3 __attribute__((address_space(3)))

__device__ __forceinline__ float bf2f(ushort h) {
    union { uint u; float f; } c; c.u = ((uint)h) << 16; return c.f;
}
__device__ __forceinline__ ushort f2bf(float f) {
    union { float f; uint u; } c; c.f = f;
    uint u = c.u;
    return (ushort)((u + 0x7FFFu + ((u >> 16) & 1u)) >> 16);  // RTNE
}

// ---------------- CSR build ----------------

__global__ void count_edges(const int* __restrict__ dst, int* __restrict__ cnt) {
    int i = blockIdx.x * blockDim.x + threadIdx.x;
    if (i < N_EDGES) atomicAdd(&cnt[dst[i]], 1);
}

// Phase 1: per-block partial sums of cnt chunks.
__global__ __launch_bounds__(SCAN_T) void scan_partial(
    const int* __restrict__ cnt, int* __restrict__ bsum, int n)
{
    int chunk = (n + SCAN_BLOCKS - 1) / SCAN_BLOCKS;
    int beg = blockIdx.x * chunk;
    int end = beg + chunk; if (end > n) end = n;
    int t = threadIdx.x;
    int s = 0;
    for (int i = beg + t; i < end; i += SCAN_T) s += cnt[i];
    __shared__ int sh[SCAN_T];
    sh[t] = s;
    __syncthreads();
    for (int off = SCAN_T / 2; off > 0; off >>= 1) {
        if (t < off) sh[t] += sh[t + off];
        __syncthreads();
    }
    if (t == 0) bsum[blockIdx.x] = sh[0];
}

// Phase 2: one tiny block exclusive-scans bsum[SCAN_BLOCKS] in place.
__global__ __launch_bounds__(SCAN_T) void scan_block_sums(int* __restrict__ bsum) {
    int t = threadIdx.x;
    __shared__ int sh[SCAN_T];
    int v = bsum[t];
    sh[t] = v;
    __syncthreads();
    for (int off = 1; off < SCAN_T; off <<= 1) {
        int u = (t >= off) ? sh[t - off] : 0;
        __syncthreads();
        sh[t] += u;
        __syncthreads();
    }
    bsum[t] = sh[t] - v;  // exclusive
}

// Phase 3: per-block local exclusive scan + block offset; writes row_ptr and
// cursor (cnt[i] := row_ptr[i]). row_ptr[n] = N_EDGES (constant).
__global__ __launch_bounds__(SCAN_T) void scan_fill(
    int* __restrict__ cnt, const int* __restrict__ bsum,
    int* __restrict__ row_ptr, int n)
{
    int chunk = (n + SCAN_BLOCKS - 1) / SCAN_BLOCKS;
    int beg = blockIdx.x * chunk;
    int end = beg + chunk; if (end > n) end = n;
    int t = threadIdx.x;
    int per = (chunk + SCAN_T - 1) / SCAN_T;
    int tb = beg + t * per;
    int te = tb + per; if (te > end) te = end;
    int s = 0;
    for (int i = tb; i < te; ++i) s += cnt[i];
    __shared__ int sh[SCAN_T];
    sh[t] = s;
    __syncthreads();
    for (int off = 1; off < SCAN_T; off <<= 1) {
        int u = (t >= off) ? sh[t - off] : 0;
        __syncthreads();
        sh[t] += u;
        __syncthreads();
    }
    int running = bsum[blockIdx.x] + sh[t] - s;  // exclusive prefix for this thread
    for (int i = tb; i < te; ++i) {
        int c = cnt[i];
        row_ptr[i] = running;
        cnt[i] = running;  // becomes fill cursor
        running += c;
    }
    if (blockIdx.x == 0 && t == 0) row_ptr[n] = N_EDGES;
}

// 4 dst-range passes (blockIdx.y): each pass's col_idx/cursor dirty region
// (~1.6MB) fits per-XCD L2, so lines collect all 16ish writes before one
// writeback instead of thrashing partial lines to HBM.
__global__ void fill_csr(const int* __restrict__ src, const int* __restrict__ dst,
                         int* __restrict__ cursor, int* __restrict__ col_idx) {
    int i = blockIdx.x * blockDim.x + threadIdx.x;
    if (i >= N_EDGES) return;
    int lo = (int)blockIdx.y * (N_NODES / FILL_PASSES);
    int hi = lo + (N_NODES / FILL_PASSES);
    int d = dst[i];
    if (d >= lo && d < hi) {
        int p = atomicAdd(&cursor[d], 1);
        col_idx[p] = src[i];
    }
}

// ---------------- conversions ----------------

__global__ void convert_x_bf16(const float* __restrict__ x, ushort* __restrict__ xb, int n4) {
    int i = blockIdx.x * blockDim.x + threadIdx.x;
    if (i >= n4) return;
    float4 v = *(const float4*)&x[(size_t)i * 4];
    ushort4 o;
    o.x = f2bf(v.x); o.y = f2bf(v.y); o.z = f2bf(v.z); o.w = f2bf(v.w);
    *(ushort4*)&xb[(size_t)i * 4] = o;
}

// W [K,256] f32 -> Wt [256,K] bf16
__global__ void transpose_w_bf16(const float* __restrict__ W, ushort* __restrict__ Wt, int kshift) {
    int i = blockIdx.x * blockDim.x + threadIdx.x;  // i = n*K + k
    int K = 1 << kshift;
    if (i >= 256 * K) return;
    int n = i >> kshift;
    int k = i & (K - 1);
    Wt[i] = f2bf(W[k * 256 + n]);
}

// ---------------- mean aggregation (bf16 gather, fp32 accum) ----------------
__global__ __launch_bounds__(64) void aggregate_bf16(
    const ushort* __restrict__ xb, const int* __restrict__ row_ptr,
    const int* __restrict__ col_idx, ushort* __restrict__ outb, int F)
{
    int node = blockIdx.x;
    int t = threadIdx.x;
    int b = row_ptr[node], e = row_ptr[node + 1];
    float d = (float)(e - b); if (d < 1.f) d = 1.f;
    float inv = 1.f / d;

    if (F == 256) {
        int c = t * 4;
        float a0 = 0.f, a1 = 0.f, a2 = 0.f, a3 = 0.f;
        float b0 = 0.f, b1 = 0.f, b2 = 0.f, b3 = 0.f;
        int i = b;
        for (; i + 1 < e; i += 2) {
            int s0 = col_idx[i];
            int s1 = col_idx[i + 1];
            uint2 v0 = *(const uint2*)&xb[(size_t)s0 * 256 + c];
            uint2 v1 = *(const uint2*)&xb[(size_t)s1 * 256 + c];
            a0 += bf2f((ushort)(v0.x & 0xffff)); a1 += bf2f((ushort)(v0.x >> 16));
            a2 += bf2f((ushort)(v0.y & 0xffff)); a3 += bf2f((ushort)(v0.y >> 16));
            b0 += bf2f((ushort)(v1.x & 0xffff)); b1 += bf2f((ushort)(v1.x >> 16));
            b2 += bf2f((ushort)(v1.y & 0xffff)); b3 += bf2f((ushort)(v1.y >> 16));
        }
        if (i < e) {
            int s0 = col_idx[i];
            uint2 v0 = *(const uint2*)&xb[(size_t)s0 * 256 + c];
            a0 += bf2f((ushort)(v0.x & 0xffff)); a1 += bf2f((ushort)(v0.x >> 16));
            a2 += bf2f((ushort)(v0.y & 0xffff)); a3 += bf2f((ushort)(v0.y >> 16));
        }
        ushort4 o;
        o.x = f2bf((a0 + b0) * inv); o.y = f2bf((a1 + b1) * inv);
        o.z = f2bf((a2 + b2) * inv); o.w = f2bf((a3 + b3) * inv);
        *(ushort4*)&outb[(size_t)node * 256 + c] = o;
    } else {
        int c = t * 2;
        float a0 = 0.f, a1 = 0.f, b0 = 0.f, b1 = 0.f;
        int i = b;
        for (; i + 1 < e; i += 2) {
            int s0 = col_idx[i];
            int s1 = col_idx[i + 1];
            uint v0 = *(const uint*)&xb[(size_t)s0 * 128 + c];
            uint v1 = *(const uint*)&xb[(size_t)s1 * 128 + c];
            a0 += bf2f((ushort)(v0 & 0xffff)); a1 += bf2f((ushort)(v0 >> 16));
            b0 += bf2f((ushort)(v1 & 0xffff)); b1 += bf2f((ushort)(v1 >> 16));
        }
        if (i < e) {
            int s0 = col_idx[i];
            uint v0 = *(const uint*)&xb[(size_t)s0 * 128 + c];
            a0 += bf2f((ushort)(v0 & 0xffff)); a1 += bf2f((ushort)(v0 >> 16));
        }
        ushort2 o;
        o.x = f2bf((a0 + b0) * inv); o.y = f2bf((a1 + b1) * inv);
        *(ushort2*)&outb[(size_t)node * 128 + c] = o;
    }
}

// ---------------- W-resident dual MFMA GEMM ----------------
// C[M,256] = relu?( A1[M,K]@W1 + A2[M,K]@W2 + bias ).
// Block: 512 thr (8 waves), tile 256 rows x 128 cols (grid.y = N-half).
// W-half for one mm lives in LDS (K/8 x 128 x 8 bf16 chunks, 64KB @K=256),
// loaded once per mm phase via global_load_lds. A-frags are loaded straight
// from global to VGPRs: a wave's 64 lanes read 16 rows x 64B contiguous —
// fully coalesced. K-loop has NO barriers and NO vmcnt drains.
__global__ __launch_bounds__(512, 4) void gemm_wres(
    const ushort* __restrict__ A1, const ushort* __restrict__ W1t,
    const ushort* __restrict__ A2, const ushort* __restrict__ W2t,
    const float* __restrict__ bias, ushort* __restrict__ out_bf,
    float* __restrict__ out_f32, int M, int K, int relu)
{
    __shared__ __align__(16) ushort Wl[32 * 128 * 8];  // 64KB, K<=256
    int tid = threadIdx.x;
    int w = tid >> 6, lane = tid & 63;
    int m_ = lane & 15, koq = lane >> 4;
    int c0 = blockIdx.y * 128;
    int row0 = blockIdx.x * 256;
    int KQ = K >> 3;               // 16B k-chunks per W column
    int nj = (KQ * 128) >> 9;      // staging rounds (slots/512)
    int nk = K >> 5;               // MFMA K-steps per mm

    floatx4 acc[2][8];
#pragma unroll
    for (int i = 0; i < 2; ++i)
#pragma unroll
        for (int f = 0; f < 8; ++f) acc[i][f] = (floatx4){0.f, 0.f, 0.f, 0.f};

    int ra = row0 + w * 32 + m_;      if (ra > M - 1) ra = M - 1;
    int rb = row0 + w * 32 + 16 + m_; if (rb > M - 1) rb = M - 1;

    for (int mm = 0; mm < 2; ++mm) {
        const ushort* __restrict__ A  = mm ? A2 : A1;
        const ushort* __restrict__ Wt = mm ? W2t : W1t;
        if (mm) __syncthreads();  // all waves done reading Wl before overwrite
        // stage W-half: slot s = q*128+col  ->  LDS byte s*16 (linear),
        // source Wt[(c0+col)*K + q*8] (per-lane address is allowed).
        for (int j = 0; j < nj; ++j) {
            int s = j * 512 + tid;
            int q = s >> 7, col = s & 127;
            __builtin_amdgcn_global_load_lds(
                (const AS1 uint*)&Wt[(size_t)(c0 + col) * K + q * 8],
                (AS3 uint*)&Wl[(size_t)(j * 512 + w * 64) * 8], 16, 0, 0);
        }
        __syncthreads();

        const ushort* __restrict__ Aa = &A[(size_t)ra * K + koq * 8];
        const ushort* __restrict__ Ab = &A[(size_t)rb * K + koq * 8];

        short8 a0 = *(const short8*)&Aa[0];
        short8 a1 = *(const short8*)&Ab[0];
        for (int kk = 0; kk < nk; ++kk) {
            short8 n0, n1;
            if (kk + 1 < nk) {            // prefetch next A-frags
                n0 = *(const short8*)&Aa[(kk + 1) * 32];
                n1 = *(const short8*)&Ab[(kk + 1) * 32];
            }
            const ushort* bbase = &Wl[(size_t)((kk * 4 + koq) * 128 + m_) * 8];
#pragma unroll
            for (int fc = 0; fc < 8; ++fc) {
                short8 b = *(const short8*)&bbase[fc * 128];  // fc*16 slots * 8
                acc[0][fc] = __builtin_amdgcn_mfma_f32_16x16x32_bf16(a0, b, acc[0][fc], 0, 0, 0);
                acc[1][fc] = __builtin_amdgcn_mfma_f32_16x16x32_bf16(a1, b, acc[1][fc], 0, 0, 0);
            }
            a0 = n0; a1 = n1;
        }
    }

    // epilogue: frag C layout col = m_, row = koq*4 + r (verified mapping)
#pragma unroll
    for (int m2 = 0; m2 < 2; ++m2) {
#pragma unroll
        for (int fc = 0; fc < 8; ++fc) {
            int col = c0 + fc * 16 + m_;
            float bv = bias[col];
#pragma unroll
            for (int r = 0; r < 4; ++r) {
                int row = row0 + w * 32 + m2 * 16 + koq * 4 + r;
                if (row >= M) continue;
                float v = acc[m2][fc][r] + bv;
                if (relu) v = fmaxf(v, 0.f);
                if (out_f32) out_f32[(size_t)row * 256 + col] = v;
                else         out_bf [(size_t)row * 256 + col] = f2bf(v);
            }
        }
    }
}

// ---------------- launch ----------------

extern "C" void kernel_launch(void* const* d_in, const int* in_sizes, int n_in,
                              void* d_out, int out_size, void* d_ws, size_t ws_size,
                              hipStream_t stream) {
    const float* x    = (const float*)d_in[0];
    const float* W_l0 = (const float*)d_in[1];
    const float* b_l0 = (const float*)d_in[2];
    const float* W_r0 = (const float*)d_in[3];
    const float* W_l1 = (const float*)d_in[4];
    const float* b_l1 = (const float*)d_in[5];
    const float* W_r1 = (const float*)d_in[6];
    const float* W_l2 = (const float*)d_in[7];
    const float* b_l2 = (const float*)d_in[8];
    const float* W_r2 = (const float*)d_in[9];
    const int* esrc   = (const int*)d_in[10];
    const int* edst   = (const int*)d_in[11];
    float* out = (float*)d_out;

    size_t off = 0;
    char* ws = (char*)d_ws;
    auto take = [&](size_t bytes) -> void* {
        void* p = ws + off;
        off += (bytes + 255) & ~(size_t)255;
        return p;
    };
    int*    cnt     = (int*)take((size_t)N_NODES * 4);
    int*    row_ptr = (int*)take((size_t)(N_NODES + 1) * 4);
    int*    col_idx = (int*)take((size_t)N_EDGES * 4);
    int*    bsum    = (int*)take((size_t)SCAN_BLOCKS * 4);
    ushort* xb      = (ushort*)take((size_t)N_NODES * 128 * 2);
    ushort* Wl0t    = (ushort*)take((size_t)256 * 128 * 2);
    ushort* Wr0t    = (ushort*)take((size_t)256 * 128 * 2);
    ushort* Wl1t    = (ushort*)take((size_t)256 * 256 * 2);
    ushort* Wr1t    = (ushort*)take((size_t)256 * 256 * 2);
    ushort* Wl2t    = (ushort*)take((size_t)256 * 256 * 2);
    ushort* Wr2t    = (ushort*)take((size_t)256 * 256 * 2);
    ushort* aggrb   = (ushort*)take((size_t)N_NODES * 256 * 2);
    ushort* ha      = (ushort*)take((size_t)N_NODES * 256 * 2);
    ushort* hb      = (ushort*)take((size_t)N_NODES * 256 * 2);
    (void)ws_size; (void)in_sizes; (void)n_in; (void)out_size;

    // CSR (hierarchical scan)
    hipMemsetAsync(cnt, 0, (size_t)N_NODES * 4, stream);
    int eb = (N_EDGES + 255) / 256;
    count_edges<<<eb, 256, 0, stream>>>(edst, cnt);
    scan_partial<<<SCAN_BLOCKS, SCAN_T, 0, stream>>>(cnt, bsum, N_NODES);
    scan_block_sums<<<1, SCAN_T, 0, stream>>>(bsum);
    scan_fill<<<SCAN_BLOCKS, SCAN_T, 0, stream>>>(cnt, bsum, row_ptr, N_NODES);
    fill_csr<<<dim3(eb, FILL_PASSES), 256, 0, stream>>>(esrc, edst, cnt, col_idx);

    // conversions
    int n4 = (N_NODES * 128) / 4;
    convert_x_bf16<<<(n4 + 255) / 256, 256, 0, stream>>>(x, xb, n4);
    transpose_w_bf16<<<(256 * 128 + 255) / 256, 256, 0, stream>>>(W_l0, Wl0t, 7);
    transpose_w_bf16<<<(256 * 128 + 255) / 256, 256, 0, stream>>>(W_r0, Wr0t, 7);
    transpose_w_bf16<<<(256 * 256 + 255) / 256, 256, 0, stream>>>(W_l1, Wl1t, 8);
    transpose_w_bf16<<<(256 * 256 + 255) / 256, 256, 0, stream>>>(W_r1, Wr1t, 8);
    transpose_w_bf16<<<(256 * 256 + 255) / 256, 256, 0, stream>>>(W_l2, Wl2t, 8);
    transpose_w_bf16<<<(256 * 256 + 255) / 256, 256, 0, stream>>>(W_r2, Wr2t, 8);

    dim3 ggrid((N_NODES + 255) / 256, 2);  // 391 row-tiles x 2 N-halves

    // layer 0: 128 -> 256, relu
    aggregate_bf16<<<N_NODES, 64, 0, stream>>>(xb, row_ptr, col_idx, aggrb, 128);
    gemm_wres<<<ggrid, 512, 0, stream>>>(aggrb, Wl0t, xb, Wr0t, b_l0,
                                         ha, nullptr, N_NODES, 128, 1);
    // layer 1: 256 -> 256, relu
    aggregate_bf16<<<N_NODES, 64, 0, stream>>>(ha, row_ptr, col_idx, aggrb, 256);
    gemm_wres<<<ggrid, 512, 0, stream>>>(aggrb, Wl1t, ha, Wr1t, b_l1,
                                         hb, nullptr, N_NODES, 256, 1);
    // layer 2: 256 -> 256, no relu, fp32 out
    aggregate_bf16<<<N_NODES, 64, 0, stream>>>(hb, row_ptr, col_idx, aggrb, 256);
    gemm_wres<<<ggrid, 512, 0, stream>>>(aggrb, Wl2t, hb, Wr2t, b_l2,
                                         nullptr, out, N_NODES, 256, 0);
}